// Round 4
// baseline (164.106 us; speedup 1.0000x reference)
//
#include <hip/hip_runtime.h>
#include <math.h>

#define NS 4096
#define NT 4096
#define RPB 8                       // rows computed per block (reads RPB+2)
#define CCH 1024                    // columns per block
#define CPT 4                       // columns per thread (256 threads * 4 = 1024)
#define NRG (NS / RPB)              // 512 row groups
#define NCC (NT / CCH)              // 4 column chunks
#define NBLK (NRG * NCC)            // 2048 blocks

__device__ __forceinline__ double block_reduce(double v, int tid) {
    #pragma unroll
    for (int off = 32; off > 0; off >>= 1)
        v += __shfl_down(v, off, 64);
    __shared__ double lds[4];
    const int lane = tid & 63, wv = tid >> 6;
    if (lane == 0) lds[wv] = v;
    __syncthreads();
    return lds[0] + lds[1] + lds[2] + lds[3];   // valid in all threads
}

// Per-row stretch metrics, computed ONCE per row. Bit-exact op sequence.
__global__ __launch_bounds__(256) void bs_rows(float4* __restrict__ t0,
                                               float4* __restrict__ t1,
                                               double C1, double C2) {
    const int r = blockIdx.x * 256 + threadIdx.x;
    if (r >= NS) return;
    const double DU = 1.0 / (double)(NS - 1);
    const double dL = C2 - C1;
    const double u   = (double)r * DU;
    const double L   = C2 * u + C1 * (1.0 - u);
    const double S   = 100.0 + 30.0 * (L * L * L / 6.0 + L);
    const double dS  = 30.0 * dL * (0.5 * L * L + 1.0);
    const double d2S = 30.0 * dL * dL * L;
    const float Sn   = (float)(S   / 300.0);
    const float Sun  = (float)(dS  / 300.0);
    const float Suun = (float)(d2S / 300.0);
    const float invSun  = 1.0f / Sun;
    const float invSun3 = invSun * invSun * invSun;
    t0[r] = make_float4(Sn * Sn, 2.5f * Sn, Sun, Suun);      // {Sn2, ASn, Sun, Suun}
    t1[r] = make_float4(invSun, invSun3, (float)u, 0.0f);    // {invSun, invSun3, u}
}

// Each block: 8 rows x 1024 cols. ALL 10 row-loads are issued up front and
// pinned live with an asm keep-alive so the register allocator cannot sink
// them (round-2 post-mortem: the compiler serialized to MLP=1, VGPR=24 ->
// 920 GB/s latency-bound). MLP=10 per wave.
__global__ __launch_bounds__(256) void bs_main(const float* __restrict__ V,
                                               const float4* __restrict__ t0,
                                               const float4* __restrict__ t1,
                                               double* __restrict__ part,
                                               unsigned* __restrict__ cnt,
                                               float* __restrict__ out) {
    const int tid = threadIdx.x;
    const int rg  = blockIdx.x >> 2;            // row group    (0..511)
    const int cc  = blockIdx.x & 3;             // column chunk (0..3)
    const int r0  = rg * RPB;
    const int j0  = cc * CCH + tid * CPT;

    const float INV2DU = 2047.5f;      // 1/(2*DU)
    const float INVDU2 = 16769025.0f;  // 1/DU^2 = 4095^2
    const float INV2DT = 102375.0f;    // 1/(2*DT_NORM)
    const float AL     = 2.5f;         // 2r/sigma^2

    const float* rowp = V + j0;

    // ---- issue all 10 row loads back-to-back (rows r0-1 .. r0+8, clamped) ----
    float4 w[10];
    #pragma unroll
    for (int i = 0; i < 10; ++i) {
        int r = r0 - 1 + i;
        r = (r < 0) ? 0 : ((r > NS - 1) ? NS - 1 : r);
        w[i] = *(const float4*)(rowp + (size_t)r * NT);
    }
    // Pin one component of each load here: forces all 10 global_load_dwordx4
    // to issue above this point in a cluster, with the waits amortized.
    // (scalar "v" operands only — float4 as "v" is an unsupported indirect input)
    asm volatile("" ::
        "v"(w[0].x), "v"(w[1].x), "v"(w[2].x), "v"(w[3].x), "v"(w[4].x),
        "v"(w[5].x), "v"(w[6].x), "v"(w[7].x), "v"(w[8].x), "v"(w[9].x));

    // clamped edge-column addresses (values unused when out of range: the
    // j-bounds checks in the inner loop mask them)
    const int jl = (j0 > 0)        ? j0 - 1   : 0;
    const int jr = (j0 + CPT < NT) ? j0 + CPT : NT - 1;

    float4 m0 = t0[r0];                 // per-row metric tables, 1-ahead prefetch
    float4 m1 = t1[r0];

    double pde = 0.0, bc = 0.0, tc = 0.0;

    #pragma unroll
    for (int rr = 0; rr < RPB; ++rr) {
        const int r = r0 + rr;

        float4 n0, n1;
        if (rr < RPB - 1) { n0 = t0[r + 1]; n1 = t1[r + 1]; }

        const float4 a = w[rr];
        const float4 b = w[rr + 1];
        const float4 c = w[rr + 2];

        if (r >= 1 && r <= NS - 2) {
            // edge neighbors: same cache lines the wave just loaded -> L1 hits
            const float lf = V[(size_t)r * NT + jl];
            const float rt = V[(size_t)r * NT + jr];

            const float aa[4] = {a.x, a.y, a.z, a.w};
            const float bb[4] = {b.x, b.y, b.z, b.w};
            const float cv[4] = {c.x, c.y, c.z, c.w};

            float pf = 0.0f;   // f32 row partial; /n_int at the end -> negligible
            #pragma unroll
            for (int k = 0; k < CPT; ++k) {
                const int j = j0 + k;
                if (j >= 1 && j <= NT - 2) {
                    const float cm = (k == 0)       ? lf : bb[k - 1];
                    const float cp = (k == CPT - 1) ? rt : bb[k + 1];
                    const float Vu  = (cv[k] - aa[k]) * INV2DU;
                    const float Vuu = (cv[k] - 2.0f * bb[k] + aa[k]) * INVDU2;
                    const float Vt  = (cp - cm) * INV2DT;
                    const float VS  = Vu * m1.x;                     // * invSun
                    float VSS = (Vuu * m0.z - Vu * m0.w) * m1.y;     // (Vuu*Sun - Vu*Suun)*invSun3
                    VSS = fminf(fmaxf(VSS, -100.0f), 100.0f);
                    const float res = Vt - m0.x * VSS - m0.y * VS + AL * bb[k];
                    pf += res * res;
                }
            }
            pde += (double)pf;
        }

        if (r == NS - 1) {
            // far-field BC at S=Smax over this thread's 4 columns
            const float bb[4] = {b.x, b.y, b.z, b.w};
            #pragma unroll
            for (int k = 0; k < CPT; ++k) {
                const float t   = (float)(j0 + k) * (1.0f / (float)(NT - 1));
                const float tgt = 1.0f - (100.0f / 300.0f) * expf(-0.05f * (1.0f - t));
                const float dd  = bb[k] - tgt;
                bc += (double)(dd * dd);
            }
        }

        if (j0 + CPT == NT) {
            // terminal condition element V[r, NT-1] == b.w
            const float ui = m1.z;
            const float x  = 50.0f * (ui - 100.0f / 300.0f);
            const float sp = fmaxf(x, 0.0f) + log1pf(expf(-fabsf(x)));
            const float payoff = sp * (1.0f / 50.0f);
            const float dd = b.w - payoff;
            const float ad = fabsf(dd);
            tc += (double)((ad < 0.01f) ? 0.5f * dd * dd : 0.01f * (ad - 0.005f));
        }

        if (rr < RPB - 1) { m0 = n0; m1 = n1; }
    }

    const double n_int = (double)(NS - 2) * (double)(NT - 2);
    double contrib = pde * (1.0 / n_int)
                   + bc  * (10.0 / (double)NT)
                   + tc  * (10.0 / (double)NS);

    contrib = block_reduce(contrib, tid);

    // ---- last-block-done cross-block reduction (no second big launch) ----
    __shared__ int amLast;
    if (tid == 0) {
        part[blockIdx.x] = contrib;
        __threadfence();                               // make part[] globally visible
        const unsigned old = atomicAdd(cnt, 1u);       // device-scope
        amLast = (old == (unsigned)(NBLK - 1));
    }
    __syncthreads();

    if (amLast) {
        double s = 0.0;
        for (int idx = tid; idx < NBLK; idx += 256)
            s += atomicAdd(&part[idx], 0.0);           // device-scope coherent read
        s = block_reduce(s, tid);
        if (tid == 0) out[0] = (float)s;
    }
}

// Host-side faithful port of CubicStretching._solve_depressed_cubic.
static double cubic_root_host(double Q) {
    const double p = 6.0;                 // CHI
    const double q = p * Q;               // CHI * Q
    const double sp = sqrt(p);
    double arg = fabs(q) / (2.0 * p * sp / (3.0 * sqrt(3.0)));
    if (arg < 1.0) arg = 1.0;
    const double c = 2.0 * sp * cosh(acosh(arg) / 3.0);
    return (q >= 0.0) ? -c : c;
}

extern "C" void kernel_launch(void* const* d_in, const int* in_sizes, int n_in,
                              void* d_out, int out_size, void* d_ws, size_t ws_size,
                              hipStream_t stream) {
    const float* V  = (const float*)d_in[0];
    float* out      = (float*)d_out;

    // workspace layout: part[NBLK] doubles | cnt | (32KB:) t0[NS] | t1[NS]
    double*   part = (double*)d_ws;
    unsigned* cnt  = (unsigned*)((char*)d_ws + NBLK * sizeof(double));
    float4*   t0   = (float4*)((char*)d_ws + 32768);
    float4*   t1   = (float4*)((char*)d_ws + 32768 + NS * sizeof(float4));

    const double C1 = cubic_root_host((100.0 - 0.0)   / 30.0);
    const double C2 = cubic_root_host((100.0 - 300.0) / 30.0);

    hipMemsetAsync(cnt, 0, sizeof(unsigned), stream);        // zero arrival counter
    bs_rows<<<(NS + 255) / 256, 256, 0, stream>>>(t0, t1, C1, C2);
    bs_main<<<NBLK, 256, 0, stream>>>(V, t0, t1, part, cnt, out);
}

// Round 5
// 126.282 us; speedup vs baseline: 1.2995x; 1.2995x over previous
//
#include <hip/hip_runtime.h>
#include <math.h>

#define NS 4096
#define NT 4096
#define RPB 4                 // rows computed per block
#define NBLK (NS / RPB)       // 1024 blocks

__device__ __forceinline__ double block_reduce(double v, int tid) {
    #pragma unroll
    for (int off = 32; off > 0; off >>= 1)
        v += __shfl_down(v, off, 64);
    __shared__ double lds[4];
    const int lane = tid & 63, wv = tid >> 6;
    if (lane == 0) lds[wv] = v;
    __syncthreads();
    return lds[0] + lds[1] + lds[2] + lds[3];   // valid in all threads
}

__device__ __forceinline__ void load16(const float* __restrict__ p, float* d) {
    const float4 x0 = *(const float4*)(p);
    const float4 x1 = *(const float4*)(p + 4);
    const float4 x2 = *(const float4*)(p + 8);
    const float4 x3 = *(const float4*)(p + 12);
    d[0]=x0.x; d[1]=x0.y; d[2]=x0.z;  d[3]=x0.w;
    d[4]=x1.x; d[5]=x1.y; d[6]=x1.z;  d[7]=x1.w;
    d[8]=x2.x; d[9]=x2.y; d[10]=x2.z; d[11]=x2.w;
    d[12]=x3.x;d[13]=x3.y;d[14]=x3.z; d[15]=x3.w;
}

// ROUND-0 PROVEN STRUCTURE (bs_main ~10-14 us ≈ HBM roofline). Each block owns
// 4 consecutive rows with a rolling 3-row register window (reads 6 rows to
// compute 4). Thread t owns 16 contiguous columns -> each dwordx4 is a
// 64-cache-line gather (lane stride 64B) = high line-level MLP per wave.
// DO NOT shrink CPT: 16->8->4 measured 10 -> 55 -> 85 us (rounds 0-2).
// Only change vs round 0: bs_final launch replaced by fused last-block tail.
__global__ __launch_bounds__(256) void bs_main(const float* __restrict__ V,
                                               double* __restrict__ part,
                                               unsigned* __restrict__ cnt,
                                               float* __restrict__ out,
                                               double C1, double C2) {
    const int tid = threadIdx.x;
    const int r0  = blockIdx.x * RPB;
    const int j0  = tid * 16;

    const double DU = 1.0 / (double)(NS - 1);
    const double dL = C2 - C1;

    const float INV2DU = 2047.5f;      // 1/(2*DU)
    const float INVDU2 = 16769025.0f;  // 1/DU^2 = 4095^2
    const float INV2DT = 102375.0f;    // 1/(2*DT_NORM)
    const float AL     = 2.5f;         // 2r/sigma^2

    float a[16], b[16], c[16];
    const int rm = (r0 > 0) ? r0 - 1 : 0;
    load16(V + (size_t)rm * NT + j0, a);
    load16(V + (size_t)r0 * NT + j0, b);

    double pde = 0.0, bc = 0.0, tc = 0.0;

    #pragma unroll
    for (int rr = 0; rr < RPB; ++rr) {
        const int r  = r0 + rr;
        const int rn = (r + 1 < NS) ? r + 1 : NS - 1;
        load16(V + (size_t)rn * NT + j0, c);

        // ---- per-row stretch metrics (f64 polynomial -> f32) ----
        const double u   = (double)r * DU;
        const double L   = C2 * u + C1 * (1.0 - u);
        const double S   = 100.0 + 30.0 * (L * L * L / 6.0 + L);
        const double dS  = 30.0 * dL * (0.5 * L * L + 1.0);
        const double d2S = 30.0 * dL * dL * L;
        const float Sn   = (float)(S   / 300.0);
        const float Sun  = (float)(dS  / 300.0);
        const float Suun = (float)(d2S / 300.0);
        const float invSun  = 1.0f / Sun;
        const float invSun3 = invSun * invSun * invSun;
        const float Sn2 = Sn * Sn;
        const float ASn = AL * Sn;

        if (r >= 1 && r <= NS - 2) {
            // horizontal edge neighbors of this thread's 16-column strip (L1 hits)
            const float lf = (j0 > 0)       ? V[(size_t)r * NT + j0 - 1]  : 0.0f;
            const float rt = (j0 + 16 < NT) ? V[(size_t)r * NT + j0 + 16] : 0.0f;

            float pf = 0.0f;   // f32 row partial; error /n_int at the end -> negligible
            #pragma unroll
            for (int k = 0; k < 16; ++k) {
                const int j = j0 + k;
                if (j >= 1 && j <= NT - 2) {
                    const float cm = (k == 0)  ? lf : b[k - 1];
                    const float cp = (k == 15) ? rt : b[k + 1];
                    const float Vu  = (c[k] - a[k]) * INV2DU;
                    const float Vuu = (c[k] - 2.0f * b[k] + a[k]) * INVDU2;
                    const float Vt  = (cp - cm) * INV2DT;
                    const float VS  = Vu * invSun;
                    float VSS = (Vuu * Sun - Vu * Suun) * invSun3;
                    VSS = fminf(fmaxf(VSS, -100.0f), 100.0f);
                    const float res = Vt - Sn2 * VSS - ASn * VS + AL * b[k];
                    pf += res * res;
                }
            }
            pde += (double)pf;
        }

        if (r == NS - 1) {
            // far-field BC at S=Smax over all columns of this row
            #pragma unroll
            for (int k = 0; k < 16; ++k) {
                const float t   = (float)(j0 + k) * (1.0f / (float)(NT - 1));
                const float tgt = 1.0f - (100.0f / 300.0f) * expf(-0.05f * (1.0f - t));
                const float d   = b[k] - tgt;
                bc += (double)(d * d);
            }
        }

        if (tid == 255) {
            // terminal condition element V[r, NT-1] == b[15]
            const float ui = (float)u;
            const float x  = 50.0f * (ui - 100.0f / 300.0f);
            const float sp = fmaxf(x, 0.0f) + log1pf(expf(-fabsf(x)));
            const float payoff = sp * (1.0f / 50.0f);
            const float d  = b[15] - payoff;
            const float ad = fabsf(d);
            tc += (double)((ad < 0.01f) ? 0.5f * d * d : 0.01f * (ad - 0.005f));
        }

        // roll the window
        #pragma unroll
        for (int k = 0; k < 16; ++k) { a[k] = b[k]; b[k] = c[k]; }
    }

    const double n_int = (double)(NS - 2) * (double)(NT - 2);
    double contrib = pde * (1.0 / n_int)
                   + bc  * (10.0 / (double)NT)
                   + tc  * (10.0 / (double)NS);

    contrib = block_reduce(contrib, tid);

    // ---- last-block-done cross-block reduction (replaces bs_final launch;
    //      bit-exact: same part[] values, same stride-256 summation order) ----
    __shared__ int amLast;
    if (tid == 0) {
        part[blockIdx.x] = contrib;
        __threadfence();                               // make part[] globally visible
        const unsigned old = atomicAdd(cnt, 1u);       // device-scope
        amLast = (old == (unsigned)(NBLK - 1));
    }
    __syncthreads();

    if (amLast) {
        double s = 0.0;
        for (int idx = tid; idx < NBLK; idx += 256)
            s += atomicAdd(&part[idx], 0.0);           // device-scope coherent read
        s = block_reduce(s, tid);
        if (tid == 0) out[0] = (float)s;
    }
}

// Host-side faithful port of CubicStretching._solve_depressed_cubic.
static double cubic_root_host(double Q) {
    const double p = 6.0;                 // CHI
    const double q = p * Q;               // CHI * Q
    const double sp = sqrt(p);
    double arg = fabs(q) / (2.0 * p * sp / (3.0 * sqrt(3.0)));
    if (arg < 1.0) arg = 1.0;
    const double c = 2.0 * sp * cosh(acosh(arg) / 3.0);
    return (q >= 0.0) ? -c : c;
}

extern "C" void kernel_launch(void* const* d_in, const int* in_sizes, int n_in,
                              void* d_out, int out_size, void* d_ws, size_t ws_size,
                              hipStream_t stream) {
    const float* V  = (const float*)d_in[0];
    float* out      = (float*)d_out;
    double* part    = (double*)d_ws;                                  // NBLK doubles
    unsigned* cnt   = (unsigned*)((char*)d_ws + NBLK * sizeof(double));

    const double C1 = cubic_root_host((100.0 - 0.0)   / 30.0);
    const double C2 = cubic_root_host((100.0 - 300.0) / 30.0);

    hipMemsetAsync(cnt, 0, sizeof(unsigned), stream);   // zero the arrival counter
    bs_main<<<NBLK, 256, 0, stream>>>(V, part, cnt, out, C1, C2);
}

// Round 6
// 102.915 us; speedup vs baseline: 1.5946x; 1.2270x over previous
//
#include <hip/hip_runtime.h>
#include <math.h>

#define NS 4096
#define NT 4096
#define RPB 2                 // rows computed per block (reads RPB+2 = 4 rows)
#define NBLK (NS / RPB)       // 2048 blocks = 8192 waves = 100% wave capacity

__device__ __forceinline__ double block_reduce(double v, int tid) {
    #pragma unroll
    for (int off = 32; off > 0; off >>= 1)
        v += __shfl_down(v, off, 64);
    __shared__ double lds[4];
    const int lane = tid & 63, wv = tid >> 6;
    if (lane == 0) lds[wv] = v;
    __syncthreads();
    return lds[0] + lds[1] + lds[2] + lds[3];   // valid in all threads
}

__device__ __forceinline__ void load16(const float* __restrict__ p, float* d) {
    const float4 x0 = *(const float4*)(p);
    const float4 x1 = *(const float4*)(p + 4);
    const float4 x2 = *(const float4*)(p + 8);
    const float4 x3 = *(const float4*)(p + 12);
    d[0]=x0.x; d[1]=x0.y; d[2]=x0.z;  d[3]=x0.w;
    d[4]=x1.x; d[5]=x1.y; d[6]=x1.z;  d[7]=x1.w;
    d[8]=x2.x; d[9]=x2.y; d[10]=x2.z; d[11]=x2.w;
    d[12]=x3.x;d[13]=x3.y;d[14]=x3.z; d[15]=x3.w;
}

// R0's proven per-wave structure (CPT=16: lane stride 64B -> max line-level MLP;
// DO NOT shrink: CPT 16->8->4 measured compute ~40 -> ~40 -> ~55+ us, rounds 0-2)
// at DOUBLE the grid: RPB=2 -> 2048 blocks = 8192 waves = full wave capacity
// (round-5 post-mortem: 1024-block grids cap occupancy at 50%, measured 30%).
// Rolling 3-row window keeps VGPR ~44-56, under the 64-VGPR/8-wave cliff.
// Fused last-block tail REMOVED: it cost ~15-17 us in serialized same-address
// device atomics (rounds 1/2/4/5); the separate 1-block bs_final is ~5 us.
__global__ __launch_bounds__(256) void bs_main(const float* __restrict__ V,
                                               double* __restrict__ part,
                                               double C1, double C2) {
    const int tid = threadIdx.x;
    const int r0  = blockIdx.x * RPB;
    const int j0  = tid * 16;

    const double DU = 1.0 / (double)(NS - 1);
    const double dL = C2 - C1;

    const float INV2DU = 2047.5f;      // 1/(2*DU)
    const float INVDU2 = 16769025.0f;  // 1/DU^2 = 4095^2
    const float INV2DT = 102375.0f;    // 1/(2*DT_NORM)
    const float AL     = 2.5f;         // 2r/sigma^2

    float a[16], b[16], c[16];
    const int rm = (r0 > 0) ? r0 - 1 : 0;
    load16(V + (size_t)rm * NT + j0, a);
    load16(V + (size_t)r0 * NT + j0, b);

    double pde = 0.0, bc = 0.0, tc = 0.0;

    #pragma unroll
    for (int rr = 0; rr < RPB; ++rr) {
        const int r  = r0 + rr;
        const int rn = (r + 1 < NS) ? r + 1 : NS - 1;
        load16(V + (size_t)rn * NT + j0, c);

        // ---- per-row stretch metrics (f64 polynomial -> f32) ----
        const double u   = (double)r * DU;
        const double L   = C2 * u + C1 * (1.0 - u);
        const double S   = 100.0 + 30.0 * (L * L * L / 6.0 + L);
        const double dS  = 30.0 * dL * (0.5 * L * L + 1.0);
        const double d2S = 30.0 * dL * dL * L;
        const float Sn   = (float)(S   / 300.0);
        const float Sun  = (float)(dS  / 300.0);
        const float Suun = (float)(d2S / 300.0);
        const float invSun  = 1.0f / Sun;
        const float invSun3 = invSun * invSun * invSun;
        const float Sn2 = Sn * Sn;
        const float ASn = AL * Sn;

        if (r >= 1 && r <= NS - 2) {
            // horizontal edge neighbors of this thread's 16-column strip (L1 hits)
            const float lf = (j0 > 0)       ? V[(size_t)r * NT + j0 - 1]  : 0.0f;
            const float rt = (j0 + 16 < NT) ? V[(size_t)r * NT + j0 + 16] : 0.0f;

            float pf = 0.0f;   // f32 row partial; error /n_int at the end -> negligible
            #pragma unroll
            for (int k = 0; k < 16; ++k) {
                const int j = j0 + k;
                if (j >= 1 && j <= NT - 2) {
                    const float cm = (k == 0)  ? lf : b[k - 1];
                    const float cp = (k == 15) ? rt : b[k + 1];
                    const float Vu  = (c[k] - a[k]) * INV2DU;
                    const float Vuu = (c[k] - 2.0f * b[k] + a[k]) * INVDU2;
                    const float Vt  = (cp - cm) * INV2DT;
                    const float VS  = Vu * invSun;
                    float VSS = (Vuu * Sun - Vu * Suun) * invSun3;
                    VSS = fminf(fmaxf(VSS, -100.0f), 100.0f);
                    const float res = Vt - Sn2 * VSS - ASn * VS + AL * b[k];
                    pf += res * res;
                }
            }
            pde += (double)pf;
        }

        if (r == NS - 1) {
            // far-field BC at S=Smax over all columns of this row
            #pragma unroll
            for (int k = 0; k < 16; ++k) {
                const float t   = (float)(j0 + k) * (1.0f / (float)(NT - 1));
                const float tgt = 1.0f - (100.0f / 300.0f) * expf(-0.05f * (1.0f - t));
                const float d   = b[k] - tgt;
                bc += (double)(d * d);
            }
        }

        if (tid == 255) {
            // terminal condition element V[r, NT-1] == b[15]
            const float ui = (float)u;
            const float x  = 50.0f * (ui - 100.0f / 300.0f);
            const float sp = fmaxf(x, 0.0f) + log1pf(expf(-fabsf(x)));
            const float payoff = sp * (1.0f / 50.0f);
            const float d  = b[15] - payoff;
            const float ad = fabsf(d);
            tc += (double)((ad < 0.01f) ? 0.5f * d * d : 0.01f * (ad - 0.005f));
        }

        // roll the window
        #pragma unroll
        for (int k = 0; k < 16; ++k) { a[k] = b[k]; b[k] = c[k]; }
    }

    const double n_int = (double)(NS - 2) * (double)(NT - 2);
    double contrib = pde * (1.0 / n_int)
                   + bc  * (10.0 / (double)NT)
                   + tc  * (10.0 / (double)NS);

    contrib = block_reduce(contrib, tid);
    if (tid == 0) part[blockIdx.x] = contrib;
}

__global__ __launch_bounds__(256) void bs_final(const double* __restrict__ part,
                                                float* __restrict__ out) {
    const int tid = threadIdx.x;
    double s = 0.0;
    for (int idx = tid; idx < NBLK; idx += 256) s += part[idx];
    s = block_reduce(s, tid);
    if (tid == 0) out[0] = (float)s;
}

// Host-side faithful port of CubicStretching._solve_depressed_cubic.
static double cubic_root_host(double Q) {
    const double p = 6.0;                 // CHI
    const double q = p * Q;               // CHI * Q
    const double sp = sqrt(p);
    double arg = fabs(q) / (2.0 * p * sp / (3.0 * sqrt(3.0)));
    if (arg < 1.0) arg = 1.0;
    const double c = 2.0 * sp * cosh(acosh(arg) / 3.0);
    return (q >= 0.0) ? -c : c;
}

extern "C" void kernel_launch(void* const* d_in, const int* in_sizes, int n_in,
                              void* d_out, int out_size, void* d_ws, size_t ws_size,
                              hipStream_t stream) {
    const float* V  = (const float*)d_in[0];
    float* out      = (float*)d_out;
    double* part    = (double*)d_ws;   // NBLK doubles, all written every launch

    const double C1 = cubic_root_host((100.0 - 0.0)   / 30.0);
    const double C2 = cubic_root_host((100.0 - 300.0) / 30.0);

    bs_main <<<NBLK, 256, 0, stream>>>(V, part, C1, C2);
    bs_final<<<1,    256, 0, stream>>>(part, out);
}

// Round 7
// 100.591 us; speedup vs baseline: 1.6314x; 1.0231x over previous
//
#include <hip/hip_runtime.h>
#include <math.h>

#define NS 4096
#define NT 4096
#define RPB 4                 // rows computed per block
#define NBLK (NS / RPB)       // 1024 blocks

// BENCH-MEASURED CONFIG SPACE (do not re-explore):
//   CPT 16->8->4 : 100 -> 125 -> 157 us total (lane stride 64B is the MLP lever)
//   fused last-block tail : +15..26 us (serialized same-address device atomics)
//   RPB 4->2 (2x grid)    : +2.8 us (halo amp 1.5->2.0; occupancy not binding)
//   load-pinning / launch_bounds min-waves : neutral-to-worse (compiler resinks)
// This file is the round-0 structure verbatim: ~16 us controllable vs ~14 us
// composed floor (64MB read @6.3TB/s = 10.2 us + final kernel + launch gaps).

__device__ __forceinline__ double block_reduce(double v, int tid) {
    #pragma unroll
    for (int off = 32; off > 0; off >>= 1)
        v += __shfl_down(v, off, 64);
    __shared__ double lds[4];
    const int lane = tid & 63, wv = tid >> 6;
    if (lane == 0) lds[wv] = v;
    __syncthreads();
    return lds[0] + lds[1] + lds[2] + lds[3];   // valid in thread 0
}

__device__ __forceinline__ void load16(const float* __restrict__ p, float* d) {
    const float4 x0 = *(const float4*)(p);
    const float4 x1 = *(const float4*)(p + 4);
    const float4 x2 = *(const float4*)(p + 8);
    const float4 x3 = *(const float4*)(p + 12);
    d[0]=x0.x; d[1]=x0.y; d[2]=x0.z;  d[3]=x0.w;
    d[4]=x1.x; d[5]=x1.y; d[6]=x1.z;  d[7]=x1.w;
    d[8]=x2.x; d[9]=x2.y; d[10]=x2.z; d[11]=x2.w;
    d[12]=x3.x;d[13]=x3.y;d[14]=x3.z; d[15]=x3.w;
}

// Each block owns 4 consecutive rows with a rolling 3-row register window:
// reads 6 rows to compute 4 (amplification 1.5x). Thread t owns 16 contiguous
// columns [t*16, t*16+16) -> each dwordx4 is a 64-cache-line gather per wave.
__global__ __launch_bounds__(256) void bs_main(const float* __restrict__ V,
                                               double* __restrict__ part,
                                               double C1, double C2) {
    const int tid = threadIdx.x;
    const int r0  = blockIdx.x * RPB;
    const int j0  = tid * 16;

    const double DU = 1.0 / (double)(NS - 1);
    const double dL = C2 - C1;

    const float INV2DU = 2047.5f;      // 1/(2*DU)
    const float INVDU2 = 16769025.0f;  // 1/DU^2 = 4095^2
    const float INV2DT = 102375.0f;    // 1/(2*DT_NORM)
    const float AL     = 2.5f;         // 2r/sigma^2

    float a[16], b[16], c[16];
    const int rm = (r0 > 0) ? r0 - 1 : 0;
    load16(V + (size_t)rm * NT + j0, a);
    load16(V + (size_t)r0 * NT + j0, b);

    double pde = 0.0, bc = 0.0, tc = 0.0;

    #pragma unroll
    for (int rr = 0; rr < RPB; ++rr) {
        const int r  = r0 + rr;
        const int rn = (r + 1 < NS) ? r + 1 : NS - 1;
        load16(V + (size_t)rn * NT + j0, c);

        // ---- per-row stretch metrics (f64 polynomial -> f32) ----
        const double u   = (double)r * DU;
        const double L   = C2 * u + C1 * (1.0 - u);
        const double S   = 100.0 + 30.0 * (L * L * L / 6.0 + L);
        const double dS  = 30.0 * dL * (0.5 * L * L + 1.0);
        const double d2S = 30.0 * dL * dL * L;
        const float Sn   = (float)(S   / 300.0);
        const float Sun  = (float)(dS  / 300.0);
        const float Suun = (float)(d2S / 300.0);
        const float invSun  = 1.0f / Sun;
        const float invSun3 = invSun * invSun * invSun;
        const float Sn2 = Sn * Sn;
        const float ASn = AL * Sn;

        if (r >= 1 && r <= NS - 2) {
            // horizontal edge neighbors of this thread's 16-column strip (L1 hits)
            const float lf = (j0 > 0)       ? V[(size_t)r * NT + j0 - 1]  : 0.0f;
            const float rt = (j0 + 16 < NT) ? V[(size_t)r * NT + j0 + 16] : 0.0f;

            float pf = 0.0f;   // f32 row partial; error /n_int at the end -> negligible
            #pragma unroll
            for (int k = 0; k < 16; ++k) {
                const int j = j0 + k;
                if (j >= 1 && j <= NT - 2) {
                    const float cm = (k == 0)  ? lf : b[k - 1];
                    const float cp = (k == 15) ? rt : b[k + 1];
                    const float Vu  = (c[k] - a[k]) * INV2DU;
                    const float Vuu = (c[k] - 2.0f * b[k] + a[k]) * INVDU2;
                    const float Vt  = (cp - cm) * INV2DT;
                    const float VS  = Vu * invSun;
                    float VSS = (Vuu * Sun - Vu * Suun) * invSun3;
                    VSS = fminf(fmaxf(VSS, -100.0f), 100.0f);
                    const float res = Vt - Sn2 * VSS - ASn * VS + AL * b[k];
                    pf += res * res;
                }
            }
            pde += (double)pf;
        }

        if (r == NS - 1) {
            // far-field BC at S=Smax over all columns of this row
            #pragma unroll
            for (int k = 0; k < 16; ++k) {
                const float t   = (float)(j0 + k) * (1.0f / (float)(NT - 1));
                const float tgt = 1.0f - (100.0f / 300.0f) * expf(-0.05f * (1.0f - t));
                const float d   = b[k] - tgt;
                bc += (double)(d * d);
            }
        }

        if (tid == 255) {
            // terminal condition element V[r, NT-1] == b[15]
            const float ui = (float)u;
            const float x  = 50.0f * (ui - 100.0f / 300.0f);
            const float sp = fmaxf(x, 0.0f) + log1pf(expf(-fabsf(x)));
            const float payoff = sp * (1.0f / 50.0f);
            const float d  = b[15] - payoff;
            const float ad = fabsf(d);
            tc += (double)((ad < 0.01f) ? 0.5f * d * d : 0.01f * (ad - 0.005f));
        }

        // roll the window
        #pragma unroll
        for (int k = 0; k < 16; ++k) { a[k] = b[k]; b[k] = c[k]; }
    }

    const double n_int = (double)(NS - 2) * (double)(NT - 2);
    double contrib = pde * (1.0 / n_int)
                   + bc  * (10.0 / (double)NT)
                   + tc  * (10.0 / (double)NS);

    contrib = block_reduce(contrib, tid);
    if (tid == 0) part[blockIdx.x] = contrib;
}

__global__ __launch_bounds__(256) void bs_final(const double* __restrict__ part,
                                                float* __restrict__ out) {
    const int tid = threadIdx.x;
    double s = 0.0;
    for (int idx = tid; idx < NBLK; idx += 256) s += part[idx];
    s = block_reduce(s, tid);
    if (tid == 0) out[0] = (float)s;
}

// Host-side faithful port of CubicStretching._solve_depressed_cubic.
static double cubic_root_host(double Q) {
    const double p = 6.0;                 // CHI
    const double q = p * Q;               // CHI * Q
    const double sp = sqrt(p);
    double arg = fabs(q) / (2.0 * p * sp / (3.0 * sqrt(3.0)));
    if (arg < 1.0) arg = 1.0;
    const double c = 2.0 * sp * cosh(acosh(arg) / 3.0);
    return (q >= 0.0) ? -c : c;
}

extern "C" void kernel_launch(void* const* d_in, const int* in_sizes, int n_in,
                              void* d_out, int out_size, void* d_ws, size_t ws_size,
                              hipStream_t stream) {
    const float* V  = (const float*)d_in[0];
    float* out      = (float*)d_out;
    double* part    = (double*)d_ws;   // NBLK doubles, all written every launch

    const double C1 = cubic_root_host((100.0 - 0.0)   / 30.0);
    const double C2 = cubic_root_host((100.0 - 300.0) / 30.0);

    bs_main <<<NBLK, 256, 0, stream>>>(V, part, C1, C2);
    bs_final<<<1,    256, 0, stream>>>(part, out);
}